// Round 4
// baseline (2282.340 us; speedup 1.0000x reference)
//
#include <hip/hip_runtime.h>

#define LROW 132  // floats per LDS tile row: 528B stride, rows r/r+8 alias = 2-way (free)

// ---------- tiny time/condition MLPs ----------
__global__ void k_tc(const float* __restrict__ t, const float* __restrict__ cond,
                     const float* __restrict__ tw1, const float* __restrict__ tb1,
                     const float* __restrict__ tw2, const float* __restrict__ tb2,
                     const float* __restrict__ cw1, const float* __restrict__ cb1,
                     const float* __restrict__ cw2, const float* __restrict__ cb2,
                     float* __restrict__ tf, float* __restrict__ cf, int B, int CDIM)
{
    __shared__ float hidT[8][128];
    __shared__ float hidC[8][128];
    int j = threadIdx.x;
    for (int b = 0; b < B; ++b) {
        hidT[b][j] = fmaxf(t[b] * tw1[j] + tb1[j], 0.f);
        float s = cb1[j];
        for (int d = 0; d < CDIM; ++d) s += cond[b * CDIM + d] * cw1[d * 128 + j];
        hidC[b][j] = fmaxf(s, 0.f);
    }
    __syncthreads();
    for (int b = 0; b < B; ++b) {
        float s1 = tb2[j], s2 = cb2[j];
        for (int k = 0; k < 128; ++k) {
            s1 += hidT[b][k] * tw2[k * 128 + j];
            s2 += hidC[b][k] * cw2[k * 128 + j];
        }
        tf[b * 128 + j] = s1;
        cf[b * 128 + j] = s2;
    }
}

// ---------- degree count ----------
__global__ void k_count(const int* __restrict__ dst, int* __restrict__ cnt, int E)
{
    int e = blockIdx.x * 256 + threadIdx.x;
    if (e < E) atomicAdd(&cnt[dst[e]], 1);
}

// ---------- scan over EVEN-PADDED counts (so each CSR segment starts int4-aligned) ----------
__global__ void k_scan1(const int* __restrict__ cnt, int* __restrict__ bsum, int N)
{
    __shared__ int s[256];
    int i = blockIdx.x * 256 + threadIdx.x;
    int c = (i < N) ? cnt[i] : 0;
    s[threadIdx.x] = (c + 1) & ~1;  // round up to even
    __syncthreads();
    for (int d = 128; d > 0; d >>= 1) {
        if (threadIdx.x < d) s[threadIdx.x] += s[threadIdx.x + d];
        __syncthreads();
    }
    if (threadIdx.x == 0) bsum[blockIdx.x] = s[0];
}

__global__ void k_scan2(const int* __restrict__ bsum, int* __restrict__ boff, int NB)
{
    __shared__ int s[512];
    int t = threadIdx.x;
    int v = (t < NB) ? bsum[t] : 0;
    s[t] = v;
    __syncthreads();
    for (int d = 1; d < 512; d <<= 1) {
        int x = (t >= d) ? s[t - d] : 0;
        __syncthreads();
        s[t] += x;
        __syncthreads();
    }
    if (t < NB) boff[t] = s[t] - v;  // exclusive block offset
}

__global__ void k_scan3(const int* __restrict__ cnt, const int* __restrict__ boff,
                        int* __restrict__ off, int N)
{
    __shared__ int s[256];
    int t = threadIdx.x;
    int i = blockIdx.x * 256 + t;
    int c = (i < N) ? cnt[i] : 0;
    int v = (c + 1) & ~1;  // even-padded
    s[t] = v;
    __syncthreads();
    for (int d = 1; d < 256; d <<= 1) {
        int x = (t >= d) ? s[t - d] : 0;
        __syncthreads();
        s[t] += x;
        __syncthreads();
    }
    if (i < N) off[i] = boff[blockIdx.x] + s[t] - v;
}

// ---------- CSR fill (packed {src, ea}) ----------
__global__ void k_fill(const int* __restrict__ src, const int* __restrict__ dst,
                       const float* __restrict__ ea, const int* __restrict__ off,
                       int* __restrict__ cur, int2* __restrict__ csr, int E)
{
    int e = blockIdx.x * 256 + threadIdx.x;
    if (e < E) {
        int d = dst[e];
        int r = atomicAdd(&cur[d], 1);
        int2 v;
        v.x = src[e];
        v.y = __float_as_int(ea[e]);
        csr[off[d] + r] = v;
    }
}

// ---------- GEMM helpers ([n][LROW] row-major LDS tile) ----------

// stage 64 global rows of 128 -> LDS, coalesced float4, zero-pad OOB rows
__device__ __forceinline__ void stage_tile(float* lds, const float* __restrict__ g,
                                           int bn0, int N, int t)
{
    for (int i = t; i < 64 * 32; i += 256) {
        int nn = i >> 5, c4 = (i & 31) * 4;
        int n = bn0 + nn;
        float4 v = {0.f, 0.f, 0.f, 0.f};
        if (n < N) v = *(const float4*)&g[(size_t)n * 128 + c4];
        *(float4*)&lds[nn * LROW + c4] = v;
    }
}

// C[n0..n0+3][j0..j0+7] += A[n][k] * W[k][j]; A from LDS rows, W from global
// (software-pipelined: W for k-group g+1 is loaded while FMAing group g)
__device__ __forceinline__ void gemm_tile(const float* lds, const float* __restrict__ W,
                                          float acc[4][8], int j0, int n0)
{
    const float* wp = W + j0;
    float4 w0a = *(const float4*)(wp + 0);
    float4 w0b = *(const float4*)(wp + 4);
    float4 w1a = *(const float4*)(wp + 128);
    float4 w1b = *(const float4*)(wp + 132);
    float4 w2a = *(const float4*)(wp + 256);
    float4 w2b = *(const float4*)(wp + 260);
    float4 w3a = *(const float4*)(wp + 384);
    float4 w3b = *(const float4*)(wp + 388);
    for (int k = 0; k < 128; k += 4) {
        // snapshot current W into wv (register renaming, compiler elides)
        float wv[4][8];
        *(float4*)&wv[0][0] = w0a; *(float4*)&wv[0][4] = w0b;
        *(float4*)&wv[1][0] = w1a; *(float4*)&wv[1][4] = w1b;
        *(float4*)&wv[2][0] = w2a; *(float4*)&wv[2][4] = w2b;
        *(float4*)&wv[3][0] = w3a; *(float4*)&wv[3][4] = w3b;
        // prefetch next k-group's W (long-latency global; in flight during FMAs)
        if (k + 4 < 128) {
            const float* np_ = wp + (size_t)(k + 4) * 128;
            w0a = *(const float4*)(np_ + 0);
            w0b = *(const float4*)(np_ + 4);
            w1a = *(const float4*)(np_ + 128);
            w1b = *(const float4*)(np_ + 132);
            w2a = *(const float4*)(np_ + 256);
            w2b = *(const float4*)(np_ + 260);
            w3a = *(const float4*)(np_ + 384);
            w3b = *(const float4*)(np_ + 388);
        }
        // A rows from LDS (b128, 2-way conflict = free)
        float4 a0 = *(const float4*)&lds[(n0 + 0) * LROW + k];
        float4 a1 = *(const float4*)&lds[(n0 + 1) * LROW + k];
        float4 a2 = *(const float4*)&lds[(n0 + 2) * LROW + k];
        float4 a3 = *(const float4*)&lds[(n0 + 3) * LROW + k];
        float av[4][4];
        *(float4*)&av[0][0] = a0;
        *(float4*)&av[1][0] = a1;
        *(float4*)&av[2][0] = a2;
        *(float4*)&av[3][0] = a3;
        #pragma unroll
        for (int nn = 0; nn < 4; ++nn)
            #pragma unroll
            for (int kk = 0; kk < 4; ++kk)
                #pragma unroll
                for (int jj = 0; jj < 8; ++jj)
                    acc[nn][jj] = fmaf(av[nn][kk], wv[kk][jj], acc[nn][jj]);
    }
}

#define ZERO_ACC(acc) \
    { _Pragma("unroll") for (int a_ = 0; a_ < 4; ++a_) \
      _Pragma("unroll") for (int b_ = 0; b_ < 8; ++b_) acc[a_][b_] = 0.f; }

// write acc(+bias) rows to global [n][128] layout
__device__ __forceinline__ void store_rows(float* out, const float acc[4][8],
                                           const float* __restrict__ bias,
                                           int bn0, int n0, int j0, int N)
{
    float bb[8];
    #pragma unroll
    for (int jj = 0; jj < 8; ++jj) bb[jj] = bias ? bias[j0 + jj] : 0.f;
    for (int nn = 0; nn < 4; ++nn) {
        int n = bn0 + n0 + nn;
        if (n >= N) continue;
        float4 o0 = {acc[nn][0] + bb[0], acc[nn][1] + bb[1], acc[nn][2] + bb[2], acc[nn][3] + bb[3]};
        float4 o1 = {acc[nn][4] + bb[4], acc[nn][5] + bb[5], acc[nn][6] + bb[6], acc[nn][7] + bb[7]};
        *(float4*)&out[(size_t)n * 128 + j0] = o0;
        *(float4*)&out[(size_t)n * 128 + j0 + 4] = o1;
    }
}

// ---------- input MLP + time/cond add + PQ of layer 0 ----------
__global__ __launch_bounds__(256, 4) void k_input_pq(
    const float* __restrict__ x, const int* __restrict__ batch,
    const float* __restrict__ w1, const float* __restrict__ b1,
    const float* __restrict__ w2, const float* __restrict__ b2,
    const float* __restrict__ tf, const float* __restrict__ cf,
    const float* __restrict__ W1n, const float* __restrict__ b1n,
    float* __restrict__ h, float* P, float* Q, int N)
{
    __shared__ float lds[64 * LROW];
    __shared__ float xs[64 * 3];
    __shared__ int   bs[64];
    int bn0 = blockIdx.x * 64;
    int t = threadIdx.x;
    if (t < 192) {
        int nn = t / 3, d = t - nn * 3;
        int n = bn0 + nn;
        xs[t] = (n < N) ? x[(size_t)n * 3 + d] : 0.f;
    }
    if (t < 64) {
        int n = bn0 + t;
        bs[t] = (n < N) ? batch[n] : 0;
    }
    __syncthreads();
    for (int idx = t; idx < 64 * 128; idx += 256) {
        int nn = idx >> 7, k = idx & 127;
        lds[nn * LROW + k] = fmaxf(xs[nn * 3] * w1[k] + xs[nn * 3 + 1] * w1[128 + k]
                                   + xs[nn * 3 + 2] * w1[256 + k] + b1[k], 0.f);
    }
    __syncthreads();
    int tx = t & 15, ty = t >> 4;
    int j0 = tx * 8, n0 = ty * 4;
    float acc[4][8];
    ZERO_ACC(acc);
    gemm_tile(lds, w2, acc, j0, n0);
    float hn[4][8];
    #pragma unroll
    for (int nn = 0; nn < 4; ++nn) {
        int b = bs[n0 + nn];
        const float* tfp = &tf[b * 128 + j0];
        const float* cfp = &cf[b * 128 + j0];
        #pragma unroll
        for (int jj = 0; jj < 8; ++jj)
            hn[nn][jj] = acc[nn][jj] + b2[j0 + jj] + tfp[jj] + cfp[jj];
    }
    for (int nn = 0; nn < 4; ++nn) {
        int n = bn0 + n0 + nn;
        if (n >= N) continue;
        float4 o0 = {hn[nn][0], hn[nn][1], hn[nn][2], hn[nn][3]};
        float4 o1 = {hn[nn][4], hn[nn][5], hn[nn][6], hn[nn][7]};
        *(float4*)&h[(size_t)n * 128 + j0] = o0;
        *(float4*)&h[(size_t)n * 128 + j0 + 4] = o1;
    }
    __syncthreads();  // tile reads done
    #pragma unroll
    for (int nn = 0; nn < 4; ++nn) {
        float4 o0 = {hn[nn][0], hn[nn][1], hn[nn][2], hn[nn][3]};
        float4 o1 = {hn[nn][4], hn[nn][5], hn[nn][6], hn[nn][7]};
        *(float4*)&lds[(n0 + nn) * LROW + j0] = o0;
        *(float4*)&lds[(n0 + nn) * LROW + j0 + 4] = o1;
    }
    __syncthreads();
    float accP[4][8];
    ZERO_ACC(accP);
    gemm_tile(lds, W1n, accP, j0, n0);
    store_rows(P, accP, b1n, bn0, n0, j0, N);
    float accQ[4][8];
    ZERO_ACC(accQ);
    gemm_tile(lds, W1n + 128 * 128, accQ, j0, n0);
    store_rows(Q, accQ, nullptr, bn0, n0, j0, N);
}

// ---------- per-layer edge aggregation: S[n] = mean_{e->n} relu(P[n]+Q[src]+ea*w1c)  (S aliases P) ----------
__global__ __launch_bounds__(256) void k_edge(
    float* PS, const float* __restrict__ Q,
    const int2* __restrict__ csr, const int* __restrict__ off, const int* __restrict__ cnt,
    const float* __restrict__ W1, int N)
{
    int n = blockIdx.x * 4 + (threadIdx.x >> 6);
    int lane = threadIdx.x & 63;
    if (n >= N) return;
    int deg = cnt[n];
    int base = off[n];  // even -> int4-aligned
    const float* w1c = W1 + 256 * 128;
    float2 p = *(const float2*)&PS[(size_t)n * 128 + lane * 2];
    float2 w = *(const float2*)&w1c[lane * 2];
    const float* Ql = Q + lane * 2;
    float accx = 0.f, accy = 0.f;
    int e = 0;
    for (; e + 8 <= deg; e += 8) {
        const int4* c4 = (const int4*)(csr + base + e);
        int4 ca = c4[0], cb = c4[1], cc = c4[2], cd = c4[3];
        float2 q0 = *(const float2*)&Ql[(size_t)ca.x * 128];
        float2 q1 = *(const float2*)&Ql[(size_t)ca.z * 128];
        float2 q2 = *(const float2*)&Ql[(size_t)cb.x * 128];
        float2 q3 = *(const float2*)&Ql[(size_t)cb.z * 128];
        float2 q4 = *(const float2*)&Ql[(size_t)cc.x * 128];
        float2 q5 = *(const float2*)&Ql[(size_t)cc.z * 128];
        float2 q6 = *(const float2*)&Ql[(size_t)cd.x * 128];
        float2 q7 = *(const float2*)&Ql[(size_t)cd.z * 128];
        float e0 = __int_as_float(ca.y), e1 = __int_as_float(ca.w);
        float e2 = __int_as_float(cb.y), e3 = __int_as_float(cb.w);
        float e4 = __int_as_float(cc.y), e5 = __int_as_float(cc.w);
        float e6 = __int_as_float(cd.y), e7 = __int_as_float(cd.w);
        accx += fmaxf(p.x + q0.x + e0 * w.x, 0.f);
        accy += fmaxf(p.y + q0.y + e0 * w.y, 0.f);
        accx += fmaxf(p.x + q1.x + e1 * w.x, 0.f);
        accy += fmaxf(p.y + q1.y + e1 * w.y, 0.f);
        accx += fmaxf(p.x + q2.x + e2 * w.x, 0.f);
        accy += fmaxf(p.y + q2.y + e2 * w.y, 0.f);
        accx += fmaxf(p.x + q3.x + e3 * w.x, 0.f);
        accy += fmaxf(p.y + q3.y + e3 * w.y, 0.f);
        accx += fmaxf(p.x + q4.x + e4 * w.x, 0.f);
        accy += fmaxf(p.y + q4.y + e4 * w.y, 0.f);
        accx += fmaxf(p.x + q5.x + e5 * w.x, 0.f);
        accy += fmaxf(p.y + q5.y + e5 * w.y, 0.f);
        accx += fmaxf(p.x + q6.x + e6 * w.x, 0.f);
        accy += fmaxf(p.y + q6.y + e6 * w.y, 0.f);
        accx += fmaxf(p.x + q7.x + e7 * w.x, 0.f);
        accy += fmaxf(p.y + q7.y + e7 * w.y, 0.f);
    }
    if (e + 4 <= deg) {
        const int4* c4 = (const int4*)(csr + base + e);
        int4 ca = c4[0], cb = c4[1];
        float2 q0 = *(const float2*)&Ql[(size_t)ca.x * 128];
        float2 q1 = *(const float2*)&Ql[(size_t)ca.z * 128];
        float2 q2 = *(const float2*)&Ql[(size_t)cb.x * 128];
        float2 q3 = *(const float2*)&Ql[(size_t)cb.z * 128];
        float e0 = __int_as_float(ca.y), e1 = __int_as_float(ca.w);
        float e2 = __int_as_float(cb.y), e3 = __int_as_float(cb.w);
        accx += fmaxf(p.x + q0.x + e0 * w.x, 0.f);
        accy += fmaxf(p.y + q0.y + e0 * w.y, 0.f);
        accx += fmaxf(p.x + q1.x + e1 * w.x, 0.f);
        accy += fmaxf(p.y + q1.y + e1 * w.y, 0.f);
        accx += fmaxf(p.x + q2.x + e2 * w.x, 0.f);
        accy += fmaxf(p.y + q2.y + e2 * w.y, 0.f);
        accx += fmaxf(p.x + q3.x + e3 * w.x, 0.f);
        accy += fmaxf(p.y + q3.y + e3 * w.y, 0.f);
        e += 4;
    }
    if (e + 2 <= deg) {
        const int4* c4 = (const int4*)(csr + base + e);
        int4 ca = c4[0];
        float2 q0 = *(const float2*)&Ql[(size_t)ca.x * 128];
        float2 q1 = *(const float2*)&Ql[(size_t)ca.z * 128];
        float e0 = __int_as_float(ca.y), e1 = __int_as_float(ca.w);
        accx += fmaxf(p.x + q0.x + e0 * w.x, 0.f);
        accy += fmaxf(p.y + q0.y + e0 * w.y, 0.f);
        accx += fmaxf(p.x + q1.x + e1 * w.x, 0.f);
        accy += fmaxf(p.y + q1.y + e1 * w.y, 0.f);
        e += 2;
    }
    if (e < deg) {
        int2 c = csr[base + e];
        float2 q = *(const float2*)&Ql[(size_t)c.x * 128];
        float ec = __int_as_float(c.y);
        accx += fmaxf(p.x + q.x + ec * w.x, 0.f);
        accy += fmaxf(p.y + q.y + ec * w.y, 0.f);
    }
    float invc = 1.f / (float)max(deg, 1);
    float2 o = {accx * invc, accy * invc};
    *(float2*)&PS[(size_t)n * 128 + lane * 2] = o;
}

// ---------- fused: h += relu(S@W2 + b2) then P,Q = h@W1next + b1next  (S aliases P!) ----------
__global__ __launch_bounds__(256, 4) void k_fused(
    float* __restrict__ h, const float* S, const int* __restrict__ cnt,
    const float* __restrict__ W2, const float* __restrict__ b2,
    const float* __restrict__ W1n, const float* __restrict__ b1n,
    float* P, float* Q, int N)
{
    __shared__ float lds[64 * LROW];
    int bn0 = blockIdx.x * 64;
    int t = threadIdx.x;
    stage_tile(lds, S, bn0, N, t);
    __syncthreads();
    int tx = t & 15, ty = t >> 4;
    int j0 = tx * 8, n0 = ty * 4;
    float acc[4][8];
    ZERO_ACC(acc);
    gemm_tile(lds, W2, acc, j0, n0);
    float hn[4][8];
    for (int nn = 0; nn < 4; ++nn) {
        int n = bn0 + n0 + nn;
        if (n < N) {
            int c = cnt[n];
            float4 h0 = *(float4*)&h[(size_t)n * 128 + j0];
            float4 h1 = *(float4*)&h[(size_t)n * 128 + j0 + 4];
            float hv[8] = {h0.x, h0.y, h0.z, h0.w, h1.x, h1.y, h1.z, h1.w};
            #pragma unroll
            for (int jj = 0; jj < 8; ++jj) {
                float agg = acc[nn][jj] + b2[j0 + jj];
                float r = (c > 0) ? fmaxf(agg, 0.f) : 0.f;
                hn[nn][jj] = hv[jj] + r;
            }
            float4 o0 = {hn[nn][0], hn[nn][1], hn[nn][2], hn[nn][3]};
            float4 o1 = {hn[nn][4], hn[nn][5], hn[nn][6], hn[nn][7]};
            *(float4*)&h[(size_t)n * 128 + j0] = o0;
            *(float4*)&h[(size_t)n * 128 + j0 + 4] = o1;
        } else {
            #pragma unroll
            for (int jj = 0; jj < 8; ++jj) hn[nn][jj] = 0.f;
        }
    }
    __syncthreads();  // S-tile reads done
    #pragma unroll
    for (int nn = 0; nn < 4; ++nn) {
        float4 o0 = {hn[nn][0], hn[nn][1], hn[nn][2], hn[nn][3]};
        float4 o1 = {hn[nn][4], hn[nn][5], hn[nn][6], hn[nn][7]};
        *(float4*)&lds[(n0 + nn) * LROW + j0] = o0;
        *(float4*)&lds[(n0 + nn) * LROW + j0 + 4] = o1;
    }
    __syncthreads();
    float accP[4][8];
    ZERO_ACC(accP);
    gemm_tile(lds, W1n, accP, j0, n0);
    store_rows(P, accP, b1n, bn0, n0, j0, N);
    float accQ[4][8];
    ZERO_ACC(accQ);
    gemm_tile(lds, W1n + 128 * 128, accQ, j0, n0);
    store_rows(Q, accQ, nullptr, bn0, n0, j0, N);
}

// ---------- final: h += relu(S@W2 + b2) then out = mlp2(h, out_w*, out_b*) ----------
__global__ __launch_bounds__(256, 4) void k_final(
    const float* __restrict__ h, const float* S, const int* __restrict__ cnt,
    const float* __restrict__ W2, const float* __restrict__ b2,
    const float* __restrict__ ow1, const float* __restrict__ ob1,
    const float* __restrict__ ow2, const float* __restrict__ ob2,
    float* __restrict__ out, int N)
{
    __shared__ float lds[64 * LROW];
    int bn0 = blockIdx.x * 64;
    int t = threadIdx.x;
    stage_tile(lds, S, bn0, N, t);
    __syncthreads();
    int tx = t & 15, ty = t >> 4;
    int j0 = tx * 8, n0 = ty * 4;
    float acc[4][8];
    ZERO_ACC(acc);
    gemm_tile(lds, W2, acc, j0, n0);
    float hn[4][8];
    for (int nn = 0; nn < 4; ++nn) {
        int n = bn0 + n0 + nn;
        if (n < N) {
            int c = cnt[n];
            float4 h0 = *(const float4*)&h[(size_t)n * 128 + j0];
            float4 h1 = *(const float4*)&h[(size_t)n * 128 + j0 + 4];
            float hv[8] = {h0.x, h0.y, h0.z, h0.w, h1.x, h1.y, h1.z, h1.w};
            #pragma unroll
            for (int jj = 0; jj < 8; ++jj) {
                float agg = acc[nn][jj] + b2[j0 + jj];
                float r = (c > 0) ? fmaxf(agg, 0.f) : 0.f;
                hn[nn][jj] = hv[jj] + r;
            }
        } else {
            #pragma unroll
            for (int jj = 0; jj < 8; ++jj) hn[nn][jj] = 0.f;
        }
    }
    __syncthreads();
    #pragma unroll
    for (int nn = 0; nn < 4; ++nn) {
        float4 o0 = {hn[nn][0], hn[nn][1], hn[nn][2], hn[nn][3]};
        float4 o1 = {hn[nn][4], hn[nn][5], hn[nn][6], hn[nn][7]};
        *(float4*)&lds[(n0 + nn) * LROW + j0] = o0;
        *(float4*)&lds[(n0 + nn) * LROW + j0 + 4] = o1;
    }
    __syncthreads();
    float acc2[4][8];
    ZERO_ACC(acc2);
    gemm_tile(lds, ow1, acc2, j0, n0);
    __syncthreads();
    #pragma unroll
    for (int nn = 0; nn < 4; ++nn) {
        float4 o0 = {fmaxf(acc2[nn][0] + ob1[j0 + 0], 0.f), fmaxf(acc2[nn][1] + ob1[j0 + 1], 0.f),
                     fmaxf(acc2[nn][2] + ob1[j0 + 2], 0.f), fmaxf(acc2[nn][3] + ob1[j0 + 3], 0.f)};
        float4 o1 = {fmaxf(acc2[nn][4] + ob1[j0 + 4], 0.f), fmaxf(acc2[nn][5] + ob1[j0 + 5], 0.f),
                     fmaxf(acc2[nn][6] + ob1[j0 + 6], 0.f), fmaxf(acc2[nn][7] + ob1[j0 + 7], 0.f)};
        *(float4*)&lds[(n0 + nn) * LROW + j0] = o0;
        *(float4*)&lds[(n0 + nn) * LROW + j0 + 4] = o1;
    }
    __syncthreads();
    if (t < 192) {
        int nn = t / 3, d = t - nn * 3;
        int n = bn0 + nn;
        if (n < N) {
            float s = ob2[d];
            for (int j = 0; j < 128; ++j) s += lds[nn * LROW + j] * ow2[j * 3 + d];
            out[(size_t)n * 3 + d] = s;
        }
    }
}

extern "C" void kernel_launch(void* const* d_in, const int* in_sizes, int n_in,
                              void* d_out, int out_size, void* d_ws, size_t ws_size,
                              hipStream_t stream)
{
    const float* x         = (const float*)d_in[0];
    const int*   edge_idx  = (const int*)d_in[1];
    const float* edge_attr = (const float*)d_in[2];
    const float* tt        = (const float*)d_in[3];
    const int*   batch     = (const int*)d_in[4];
    const float* cond      = (const float*)d_in[5];
    const float* in_w1 = (const float*)d_in[6],  *in_b1 = (const float*)d_in[7];
    const float* in_w2 = (const float*)d_in[8],  *in_b2 = (const float*)d_in[9];
    const float* t_w1  = (const float*)d_in[10], *t_b1  = (const float*)d_in[11];
    const float* t_w2  = (const float*)d_in[12], *t_b2  = (const float*)d_in[13];
    const float* c_w1  = (const float*)d_in[14], *c_b1  = (const float*)d_in[15];
    const float* c_w2  = (const float*)d_in[16], *c_b2  = (const float*)d_in[17];
    const float* convW1 = (const float*)d_in[18], *convb1 = (const float*)d_in[19];
    const float* convW2 = (const float*)d_in[20], *convb2 = (const float*)d_in[21];
    const float* out_w1 = (const float*)d_in[22], *out_b1 = (const float*)d_in[23];
    const float* out_w2 = (const float*)d_in[24], *out_b2 = (const float*)d_in[25];

    const int N = in_sizes[0] / 3;
    const int E = in_sizes[1] / 2;
    const int B = in_sizes[3];
    const int CDIM = in_sizes[5] / B;
    const int L = in_sizes[19] / 128;

    const int* esrc = edge_idx;
    const int* edst = edge_idx + E;

    char* w = (char*)d_ws;
    auto alloc = [&](size_t bytes) -> char* {
        char* p = w;
        w += (bytes + 255) & ~(size_t)255;
        return p;
    };
    float* h    = (float*)alloc((size_t)N * 128 * 4);
    float* P    = (float*)alloc((size_t)N * 128 * 4);   // also S (aliased)
    float* Q    = (float*)alloc((size_t)N * 128 * 4);
    int*   cnt  = (int*)alloc((size_t)N * 4);
    int*   cur  = (int*)alloc((size_t)N * 4);
    int*   off  = (int*)alloc((size_t)N * 4);
    int*   bsum = (int*)alloc(4096);
    int*   boff = (int*)alloc(4096);
    int2*  csr  = (int2*)alloc(((size_t)E + N + 8) * 8);  // even-padded segments
    float* tf   = (float*)alloc((size_t)B * 128 * 4);
    float* cf   = (float*)alloc((size_t)B * 128 * 4);

    hipMemsetAsync(cnt, 0, (size_t)N * 4, stream);
    hipMemsetAsync(cur, 0, (size_t)N * 4, stream);

    k_tc<<<1, 128, 0, stream>>>(tt, cond, t_w1, t_b1, t_w2, t_b2,
                                c_w1, c_b1, c_w2, c_b2, tf, cf, B, CDIM);

    const int eb = (E + 255) / 256;
    const int nb = (N + 255) / 256;
    k_count<<<eb, 256, 0, stream>>>(edst, cnt, E);
    k_scan1<<<nb, 256, 0, stream>>>(cnt, bsum, N);
    k_scan2<<<1, 512, 0, stream>>>(bsum, boff, nb);
    k_scan3<<<nb, 256, 0, stream>>>(cnt, boff, off, N);
    k_fill<<<eb, 256, 0, stream>>>(esrc, edst, edge_attr, off, cur, csr, E);

    const int gnodes = (N + 63) / 64;
    k_input_pq<<<gnodes, 256, 0, stream>>>(x, batch, in_w1, in_b1, in_w2, in_b2,
                                           tf, cf, convW1, convb1, h, P, Q, N);

    for (int i = 0; i < L; ++i) {
        const float* W1 = convW1 + (size_t)i * 257 * 128;
        const float* b1 = convb1 + (size_t)i * 128;
        const float* W2 = convW2 + (size_t)i * 128 * 128;
        const float* b2 = convb2 + (size_t)i * 128;
        k_edge<<<(N + 3) / 4, 256, 0, stream>>>(P, Q, csr, off, cnt, W1, N);
        if (i < L - 1) {
            const float* W1n = convW1 + (size_t)(i + 1) * 257 * 128;
            const float* b1n = convb1 + (size_t)(i + 1) * 128;
            k_fused<<<gnodes, 256, 0, stream>>>(h, P, cnt, W2, b2, W1n, b1n, P, Q, N);
        } else {
            k_final<<<gnodes, 256, 0, stream>>>(h, P, cnt, W2, b2,
                                                out_w1, out_b1, out_w2, out_b2,
                                                (float*)d_out, N);
        }
    }
}